// Round 1
// baseline (1721.307 us; speedup 1.0000x reference)
//
#include <hip/hip_runtime.h>
#include <stdint.h>
#include <stddef.h>

#define DV 5000
#define DD 256
#define DI 2048
#define DU 50
#define DT 200
#define DB 2
#define MROWS (DB*DT*DU)   // 20000
#define BM 128
#define BN 128
#define BK 32
#define MT 157             // ceil(20000/128)
#define NT 40              // ceil(5000/128)
#define MPAD (MT*BM)       // 20096
#define NPAD (NT*BN)       // 5120
#define KD DI              // 2048
#define LSTM_BLOCKS 16

using f32x4  = __attribute__((ext_vector_type(4))) float;
using bf16x8 = __attribute__((ext_vector_type(8))) short;

typedef __attribute__((address_space(1))) const unsigned int as1_cuint;
typedef __attribute__((address_space(3))) unsigned int as3_uint;

__device__ __forceinline__ float fsig(float x)  { return 1.0f / (1.0f + __expf(-x)); }
__device__ __forceinline__ float ftanh(float x) { return 1.0f - 2.0f / (1.0f + __expf(2.0f * x)); }
__device__ __forceinline__ uint16_t f2bf(float x) {  // RNE float->bf16 (finite inputs)
  uint32_t u = __float_as_uint(x);
  u += 0x7FFFu + ((u >> 16) & 1u);
  return (uint16_t)(u >> 16);
}

__device__ __forceinline__ void gload_lds16(const void* g, void* l) {
  __builtin_amdgcn_global_load_lds((as1_cuint*)g, (as3_uint*)l, 16, 0, 0);
}

// ---------------------------------------------------------------------------
// Xg[t][b][r] = b_ih[r] + b_hh[r] + dot(emb[ys[b][t]], W_ih[r])
__global__ void __launch_bounds__(256) xg_kernel(
    const int* __restrict__ ys, const float* __restrict__ emb,
    const float* __restrict__ W_ih, const float* __restrict__ b_ih,
    const float* __restrict__ b_hh, float* __restrict__ Xg) {
  int blk = blockIdx.x;            // = u*DB + b
  int u = blk / DB, b = blk % DB;
  __shared__ float xr[DD];
  int tok = ys[b * DU + u];
  const float* er = emb + (size_t)tok * DD;
  for (int j = threadIdx.x; j < DD; j += 256) xr[j] = er[j];
  __syncthreads();
  for (int r = threadIdx.x; r < 4 * DD; r += 256) {
    const float4* w4 = (const float4*)(W_ih + (size_t)r * DD);
    float s = 0.f;
    #pragma unroll 8
    for (int k4 = 0; k4 < DD / 4; ++k4) {
      float4 wv = w4[k4];
      const float4 xv = *(const float4*)&xr[k4 * 4];
      s += wv.x * xv.x + wv.y * xv.y + wv.z * xv.z + wv.w * xv.w;
    }
    Xg[((size_t)u * DB + b) * 1024 + r] = s + b_ih[r] + b_hh[r];
  }
}

// ---------------------------------------------------------------------------
// Persistent LSTM: 16 blocks, each owns 64 gate rows; gates exchanged via
// double-buffered global gbuf with agent-scope release/acquire spin sync.
__global__ void __launch_bounds__(256) lstm_kernel(
    const float* __restrict__ Xg, const float* __restrict__ W_hh,
    float* __restrict__ hs, float* __restrict__ gbuf, int* __restrict__ syncp) {
  __shared__ float Wt[DD][64];   // transposed W slice [k][row], 64 KB
  __shared__ float hl[DB][DD];
  __shared__ float cl[DB][DD];
  const int tid = threadIdx.x;
  const int blk = blockIdx.x;
  const int r0 = blk * 64;
  for (int idx = tid; idx < 64 * DD; idx += 256) {
    int rl = idx & 63, k = idx >> 6;
    Wt[k][rl] = W_hh[(size_t)(r0 + rl) * DD + k];
  }
  for (int idx = tid; idx < DB * DD; idx += 256) {
    (&hl[0][0])[idx] = 0.f; (&cl[0][0])[idx] = 0.f;
  }
  __syncthreads();
  const int p = tid >> 1, half = tid & 1;
  const int db = p >> 6;         // batch
  const int rl = p & 63;         // local gate row
  const int kb = half * 128;
  for (int t = 0; t < DU; ++t) {
    // ---- gate slice: gates[db][r0+rl] = Xg[t][db][r0+rl] + dot(h[db], W[r0+rl])
    float s0 = 0.f, s1 = 0.f, s2 = 0.f, s3 = 0.f;
    #pragma unroll 8
    for (int k = 0; k < 128; k += 4) {
      s0 += hl[db][kb + k    ] * Wt[kb + k    ][rl];
      s1 += hl[db][kb + k + 1] * Wt[kb + k + 1][rl];
      s2 += hl[db][kb + k + 2] * Wt[kb + k + 2][rl];
      s3 += hl[db][kb + k + 3] * Wt[kb + k + 3][rl];
    }
    float s = (s0 + s1) + (s2 + s3);
    s += __shfl_xor(s, 1);
    float* gb = gbuf + (t & 1) * (DB * 1024);
    if (half == 0)
      gb[db * 1024 + r0 + rl] = Xg[((size_t)t * DB + db) * 1024 + (r0 + rl)] + s;
    __threadfence();             // flush gate stores device-wide
    __syncthreads();
    if (tid == 0) {
      __hip_atomic_fetch_add(syncp, 1, __ATOMIC_RELEASE, __HIP_MEMORY_SCOPE_AGENT);
      const int target = LSTM_BLOCKS * (t + 1);
      while (__hip_atomic_load(syncp, __ATOMIC_ACQUIRE, __HIP_MEMORY_SCOPE_AGENT) < target)
        __builtin_amdgcn_s_sleep(2);
    }
    __syncthreads();
    // ---- elementwise update (redundant per block), j = tid
    {
      int j = tid;
      #pragma unroll
      for (int b = 0; b < DB; ++b) {
        const float* g = gb + b * 1024;
        float gi = g[j], gf = g[256 + j], gg = g[512 + j], go = g[768 + j];
        float c = fsig(gf) * cl[b][j] + fsig(gi) * ftanh(gg);
        float h = fsig(go) * ftanh(c);
        cl[b][j] = c;
        hl[b][j] = h;
        if (blk == 0) hs[((size_t)b * DU + t) * DD + j] = h;
      }
    }
    __syncthreads();
  }
}

// ---------------------------------------------------------------------------
// x2 = LayerNorm(hs @ W_proj^T + b_proj) ; one block per (b,u) row, 256 thr
__global__ void __launch_bounds__(256) proj_ln_kernel(
    const float* __restrict__ hs, const float* __restrict__ W_proj,
    const float* __restrict__ b_proj, const float* __restrict__ ln_g,
    const float* __restrict__ ln_b, float* __restrict__ x2) {
  int blk = blockIdx.x;          // b*DU + u
  __shared__ float xr[DD];
  __shared__ float red1[4], red2[4];
  int j = threadIdx.x;
  xr[j] = hs[(size_t)blk * DD + j];
  __syncthreads();
  const float4* w4 = (const float4*)(W_proj + (size_t)j * DD);
  float s = b_proj[j];
  #pragma unroll 8
  for (int k4 = 0; k4 < DD / 4; ++k4) {
    float4 wv = w4[k4];
    const float4 xv = *(const float4*)&xr[k4 * 4];
    s += wv.x * xv.x + wv.y * xv.y + wv.z * xv.z + wv.w * xv.w;
  }
  float v = s;
  float sum = v;
  #pragma unroll
  for (int o = 1; o < 64; o <<= 1) sum += __shfl_xor(sum, o);
  if ((j & 63) == 0) red1[j >> 6] = sum;
  __syncthreads();
  float mu = (red1[0] + red1[1] + red1[2] + red1[3]) * (1.0f / DD);
  float d = v - mu;
  float sq = d * d;
  #pragma unroll
  for (int o = 1; o < 64; o <<= 1) sq += __shfl_xor(sq, o);
  if ((j & 63) == 0) red2[j >> 6] = sq;
  __syncthreads();
  float var = (red2[0] + red2[1] + red2[2] + red2[3]) * (1.0f / DD);
  x2[(size_t)blk * DD + j] = d * rsqrtf(var + 1e-5f) * ln_g[j] + ln_b[j];
}

// ---------------------------------------------------------------------------
// Y[row] = X[row] @ W^T + bias ; W is [DI][DD] ; one block per row
__global__ void __launch_bounds__(256) lin2048_kernel(
    const float* __restrict__ X, const float* __restrict__ W,
    const float* __restrict__ bias, float* __restrict__ Y) {
  int row = blockIdx.x;
  __shared__ float xr[DD];
  if (threadIdx.x < DD) xr[threadIdx.x] = X[(size_t)row * DD + threadIdx.x];
  __syncthreads();
  for (int o = threadIdx.x; o < DI; o += 256) {
    const float4* w4 = (const float4*)(W + (size_t)o * DD);
    float s = bias[o];
    #pragma unroll 8
    for (int k4 = 0; k4 < DD / 4; ++k4) {
      float4 wv = w4[k4];
      const float4 xv = *(const float4*)&xr[k4 * 4];
      s += wv.x * xv.x + wv.y * xv.y + wv.z * xv.z + wv.w * xv.w;
    }
    Y[(size_t)row * DI + o] = s;
  }
}

// ---------------------------------------------------------------------------
// W_out fp32 [5000][2048] -> bf16 [NPAD][2048], zero-padded rows
__global__ void __launch_bounds__(256) wout_cvt_kernel(
    const float* __restrict__ W, uint16_t* __restrict__ Wb) {
  int n = blockIdx.x;
  int k8 = threadIdx.x * 8;
  uint16_t* row = Wb + (size_t)n * KD;
  if (n >= DV) { *(uint4*)(row + k8) = make_uint4(0, 0, 0, 0); return; }
  const float* w = W + (size_t)n * KD + k8;
  float4 a = *(const float4*)w, b = *(const float4*)(w + 4);
  uint32_t p0 = (uint32_t)f2bf(a.x) | ((uint32_t)f2bf(a.y) << 16);
  uint32_t p1 = (uint32_t)f2bf(a.z) | ((uint32_t)f2bf(a.w) << 16);
  uint32_t p2 = (uint32_t)f2bf(b.x) | ((uint32_t)f2bf(b.y) << 16);
  uint32_t p3 = (uint32_t)f2bf(b.z) | ((uint32_t)f2bf(b.w) << 16);
  *(uint4*)(row + k8) = make_uint4(p0, p1, p2, p3);
}

// ---------------------------------------------------------------------------
// jnt[m][k] = bf16(tanh(enc[b,t,k] + dec[b,u,k])), m = b*10000 + t*50 + u
__global__ void __launch_bounds__(256) jnt_kernel(
    const float* __restrict__ enc, const float* __restrict__ dec,
    uint16_t* __restrict__ J) {
  int m = blockIdx.x;
  int k8 = threadIdx.x * 8;
  uint16_t* row = J + (size_t)m * KD;
  if (m >= MROWS) { *(uint4*)(row + k8) = make_uint4(0, 0, 0, 0); return; }
  int b = m / (DT * DU); int rm = m % (DT * DU); int t = rm / DU; int u = rm % DU;
  const float* e = enc + ((size_t)b * DT + t) * KD + k8;
  const float* d = dec + ((size_t)b * DU + u) * KD + k8;
  float4 e0 = *(const float4*)e, e1 = *(const float4*)(e + 4);
  float4 d0 = *(const float4*)d, d1 = *(const float4*)(d + 4);
  float v0 = ftanh(e0.x + d0.x), v1 = ftanh(e0.y + d0.y);
  float v2 = ftanh(e0.z + d0.z), v3 = ftanh(e0.w + d0.w);
  float v4 = ftanh(e1.x + d1.x), v5 = ftanh(e1.y + d1.y);
  float v6 = ftanh(e1.z + d1.z), v7 = ftanh(e1.w + d1.w);
  uint32_t p0 = (uint32_t)f2bf(v0) | ((uint32_t)f2bf(v1) << 16);
  uint32_t p1 = (uint32_t)f2bf(v2) | ((uint32_t)f2bf(v3) << 16);
  uint32_t p2 = (uint32_t)f2bf(v4) | ((uint32_t)f2bf(v5) << 16);
  uint32_t p3 = (uint32_t)f2bf(v6) | ((uint32_t)f2bf(v7) << 16);
  *(uint4*)(row + k8) = make_uint4(p0, p1, p2, p3);
}

// ---------------------------------------------------------------------------
// C[m][n] = jnt[m,:] @ Wout[n,:] + b_out[n]  (m97-style 128x128 bf16 GEMM)
__global__ void __launch_bounds__(256) gemm_kernel(
    const uint16_t* __restrict__ A, const uint16_t* __restrict__ Bm,
    const float* __restrict__ b_out, float* __restrict__ C) {
  __shared__ __align__(16) uint16_t As[BM * BK];  // 8 KB
  __shared__ __align__(16) uint16_t Bs[BN * BK];  // 8 KB
  int bid = blockIdx.x;
  const int nwg = MT * NT, cpx = nwg >> 3;        // 6280 % 8 == 0
  int wg = (bid & 7) * cpx + (bid >> 3);          // XCD swizzle
  int mt = wg / NT, nt = wg % NT;
  const int m0 = mt * BM, n0 = nt * BN;
  const int tid = threadIdx.x;
  const int lane = tid & 63, wv = tid >> 6;
  const int wm = wv >> 1, wn = wv & 1;
  const char* Ab = (const char*)A;
  const char* Bb = (const char*)Bm;
  char* Asb = (char*)As;
  char* Bsb = (char*)Bs;
  f32x4 acc[4][4] = {};
  for (int k0 = 0; k0 < KD; k0 += BK) {
    #pragma unroll
    for (int it = 0; it < 2; ++it) {
      int g = wv * 2 + it;                 // chunk group: bytes [g*1024, +1024)
      int o = g * 1024 + lane * 16;
      int row = o >> 6, colb = o & 63;     // 64 B per tile row (32 bf16)
      gload_lds16(Ab + ((size_t)(m0 + row) * KD + k0) * 2 + colb, Asb + g * 1024);
      gload_lds16(Bb + ((size_t)(n0 + row) * KD + k0) * 2 + colb, Bsb + g * 1024);
    }
    __syncthreads();
    bf16x8 af[4], bfr[4];
    #pragma unroll
    for (int i = 0; i < 4; ++i) {
      af[i]  = *(const bf16x8*)(Asb + (wm * 64 + i * 16 + (lane & 15)) * 64 + ((lane >> 4) << 4));
      bfr[i] = *(const bf16x8*)(Bsb + (wn * 64 + i * 16 + (lane & 15)) * 64 + ((lane >> 4) << 4));
    }
    #pragma unroll
    for (int i = 0; i < 4; ++i)
      #pragma unroll
      for (int j = 0; j < 4; ++j)
        acc[i][j] = __builtin_amdgcn_mfma_f32_16x16x32_bf16(af[i], bfr[j], acc[i][j], 0, 0, 0);
    __syncthreads();
  }
  // epilogue: C/D layout col = lane&15, row = (lane>>4)*4 + reg
  const int cr = lane >> 4, cc = lane & 15;
  #pragma unroll
  for (int j = 0; j < 4; ++j) {
    int n = n0 + wn * 64 + j * 16 + cc;
    if (n >= DV) continue;
    float bo = b_out[n];
    #pragma unroll
    for (int i = 0; i < 4; ++i) {
      #pragma unroll
      for (int r = 0; r < 4; ++r) {
        int m = m0 + wm * 64 + i * 16 + cr * 4 + r;
        if (m < MROWS) C[(size_t)m * DV + n] = acc[i][j][r] + bo;
      }
    }
  }
}

// ---------------------------------------------------------------------------
// in-place row log_softmax over V=5000 ; one block (256 thr) per row
__global__ void __launch_bounds__(256) lsm_kernel(float* __restrict__ C) {
  int m = blockIdx.x;
  float* row = C + (size_t)m * DV;
  __shared__ float4 buf4[DV / 4];          // 20000 B
  __shared__ float redm[4], reds[4];
  int tid = threadIdx.x;
  float mx = -3.4e38f;
  for (int v = tid; v < DV / 4; v += 256) {
    float4 x = *(const float4*)(row + v * 4);
    buf4[v] = x;
    mx = fmaxf(fmaxf(mx, fmaxf(x.x, x.y)), fmaxf(x.z, x.w));
  }
  #pragma unroll
  for (int o = 1; o < 64; o <<= 1) mx = fmaxf(mx, __shfl_xor(mx, o));
  if ((tid & 63) == 0) redm[tid >> 6] = mx;
  __syncthreads();
  mx = fmaxf(fmaxf(redm[0], redm[1]), fmaxf(redm[2], redm[3]));
  float s = 0.f;
  for (int v = tid; v < DV / 4; v += 256) {
    float4 x = buf4[v];
    s += __expf(x.x - mx) + __expf(x.y - mx) + __expf(x.z - mx) + __expf(x.w - mx);
  }
  #pragma unroll
  for (int o = 1; o < 64; o <<= 1) s += __shfl_xor(s, o);
  if ((tid & 63) == 0) reds[tid >> 6] = s;
  __syncthreads();
  s = reds[0] + reds[1] + reds[2] + reds[3];
  float lse = mx + __logf(s);
  for (int v = tid; v < DV / 4; v += 256) {
    float4 x = buf4[v];
    x.x -= lse; x.y -= lse; x.z -= lse; x.w -= lse;
    *(float4*)(row + v * 4) = x;
  }
}

// ---------------------------------------------------------------------------
static constexpr size_t ALGN(size_t x) { return (x + 255) & ~(size_t)255; }
static constexpr size_t OFF_XG   = 0;
static constexpr size_t SZ_XG    = (size_t)DU * DB * 1024 * 4;
static constexpr size_t OFF_HS   = ALGN(OFF_XG + SZ_XG);
static constexpr size_t SZ_HS    = (size_t)DB * DU * DD * 4;
static constexpr size_t OFF_X2   = ALGN(OFF_HS + SZ_HS);
static constexpr size_t OFF_ENC  = ALGN(OFF_X2 + SZ_HS);
static constexpr size_t SZ_ENC   = (size_t)DB * DT * DI * 4;
static constexpr size_t OFF_DEC  = ALGN(OFF_ENC + SZ_ENC);
static constexpr size_t SZ_DEC   = (size_t)DB * DU * DI * 4;
static constexpr size_t OFF_GB   = ALGN(OFF_DEC + SZ_DEC);
static constexpr size_t SZ_GB    = (size_t)2 * DB * 1024 * 4;
static constexpr size_t OFF_SYNC = ALGN(OFF_GB + SZ_GB);
static constexpr size_t OFF_WOB  = ALGN(OFF_SYNC + 256);
static constexpr size_t SZ_WOB   = (size_t)NPAD * KD * 2;
static constexpr size_t OFF_JNT  = ALGN(OFF_WOB + SZ_WOB);

extern "C" void kernel_launch(void* const* d_in, const int* in_sizes, int n_in,
                              void* d_out, int out_size, void* d_ws, size_t ws_size,
                              hipStream_t stream) {
  const float* memory = (const float*)d_in[0];
  const int*   ys     = (const int*)d_in[1];
  // d_in[2] = ys_in_lens (unused by the reference output)
  const float* emb    = (const float*)d_in[3];
  const float* W_ih   = (const float*)d_in[4];
  const float* b_ih   = (const float*)d_in[5];
  const float* W_hh   = (const float*)d_in[6];
  const float* b_hh   = (const float*)d_in[7];
  const float* W_proj = (const float*)d_in[8];
  const float* b_proj = (const float*)d_in[9];
  const float* ln_g   = (const float*)d_in[10];
  const float* ln_b   = (const float*)d_in[11];
  const float* W_enc  = (const float*)d_in[12];
  const float* b_enc  = (const float*)d_in[13];
  const float* W_prd  = (const float*)d_in[14];
  const float* b_prd  = (const float*)d_in[15];
  const float* W_out  = (const float*)d_in[16];
  const float* b_out  = (const float*)d_in[17];

  char* ws = (char*)d_ws;
  float*    Xg   = (float*)(ws + OFF_XG);
  float*    hs   = (float*)(ws + OFF_HS);
  float*    x2   = (float*)(ws + OFF_X2);
  float*    enc  = (float*)(ws + OFF_ENC);
  float*    dec  = (float*)(ws + OFF_DEC);
  float*    gbuf = (float*)(ws + OFF_GB);
  int*      sy   = (int*)(ws + OFF_SYNC);
  uint16_t* Wob  = (uint16_t*)(ws + OFF_WOB);
  uint16_t* jnt  = (uint16_t*)(ws + OFF_JNT);
  float*    C    = (float*)d_out;

  hipMemsetAsync(sy, 0, 256, stream);
  xg_kernel<<<DU * DB, 256, 0, stream>>>(ys, emb, W_ih, b_ih, b_hh, Xg);
  lstm_kernel<<<LSTM_BLOCKS, 256, 0, stream>>>(Xg, W_hh, hs, gbuf, sy);
  proj_ln_kernel<<<DB * DU, 256, 0, stream>>>(hs, W_proj, b_proj, ln_g, ln_b, x2);
  lin2048_kernel<<<DB * DT, 256, 0, stream>>>(memory, W_enc, b_enc, enc);
  lin2048_kernel<<<DB * DU, 256, 0, stream>>>(x2, W_prd, b_prd, dec);
  wout_cvt_kernel<<<NPAD, 256, 0, stream>>>(W_out, Wob);
  jnt_kernel<<<MPAD, 256, 0, stream>>>(enc, dec, jnt);
  gemm_kernel<<<MT * NT, 256, 0, stream>>>(jnt, Wob, b_out, C);
  lsm_kernel<<<MROWS, 256, 0, stream>>>(C);
}